// Round 1
// baseline (453.025 us; speedup 1.0000x reference)
//
#include <hip/hip_runtime.h>
#include <hip/hip_bf16.h>
#include <stdint.h>

#define N_ROWS 8192
#define DIM    1024
#define BM 128
#define BN 128
#define BK 64

typedef __bf16 bf16_t;
typedef __bf16 bf16x4 __attribute__((ext_vector_type(4)));
typedef __bf16 bf16x8 __attribute__((ext_vector_type(8)));
typedef float  f32x4  __attribute__((ext_vector_type(4)));

// ---------------------------------------------------------------------------
// Kernel 1: fused L2-normalize (fp32 -> bf16) + exact fp32 diagonal dot.
// One block per row; 256 threads x float4 = 1024 elements.
// ---------------------------------------------------------------------------
__global__ __launch_bounds__(256) void nrm_kernel(
    const float* __restrict__ img, const float* __restrict__ txt,
    bf16_t* __restrict__ img_n, bf16_t* __restrict__ txt_n,
    float* __restrict__ diag_sum)
{
    const int row  = blockIdx.x;
    const int t    = threadIdx.x;
    const int lane = t & 63;
    const int w    = t >> 6;

    const float4 a = ((const float4*)(img + (size_t)row * DIM))[t];
    const float4 b = ((const float4*)(txt + (size_t)row * DIM))[t];

    float sa = a.x * a.x + a.y * a.y + a.z * a.z + a.w * a.w;
    float sb = b.x * b.x + b.y * b.y + b.z * b.z + b.w * b.w;
#pragma unroll
    for (int d = 1; d < 64; d <<= 1) {
        sa += __shfl_xor(sa, d, 64);
        sb += __shfl_xor(sb, d, 64);
    }
    __shared__ float red[3][4];
    if (lane == 0) { red[0][w] = sa; red[1][w] = sb; }
    __syncthreads();
    sa = red[0][0] + red[0][1] + red[0][2] + red[0][3];
    sb = red[1][0] + red[1][1] + red[1][2] + red[1][3];

    const float ia = 1.0f / fmaxf(sqrtf(sa), 1e-12f);
    const float ib = 1.0f / fmaxf(sqrtf(sb), 1e-12f);

    bf16x4 av, bv;
    av.x = (bf16_t)(a.x * ia); av.y = (bf16_t)(a.y * ia);
    av.z = (bf16_t)(a.z * ia); av.w = (bf16_t)(a.w * ia);
    bv.x = (bf16_t)(b.x * ib); bv.y = (bf16_t)(b.y * ib);
    bv.z = (bf16_t)(b.z * ib); bv.w = (bf16_t)(b.w * ib);
    ((bf16x4*)(img_n + (size_t)row * DIM))[t] = av;
    ((bf16x4*)(txt_n + (size_t)row * DIM))[t] = bv;

    // exact fp32 diagonal (positives)
    float dp = (a.x * b.x + a.y * b.y + a.z * b.z + a.w * b.w) * ia * ib;
#pragma unroll
    for (int d = 1; d < 64; d <<= 1) dp += __shfl_xor(dp, d, 64);
    if (lane == 0) red[2][w] = dp;
    __syncthreads();
    if (t == 0) atomicAdd(diag_sum, red[2][0] + red[2][1] + red[2][2] + red[2][3]);
}

// ---------------------------------------------------------------------------
// Kernel 2: 128x128-tile bf16 MFMA GEMM (C = A . B^T, both row-major [N,D]),
// fused epilogue: rowsum of exp(sim - 1) -> atomicAdd into S[row].
// m97 structure: global_load_lds width=16, ds_read_b128 fragments.
// ---------------------------------------------------------------------------
__global__ __launch_bounds__(256) void sim_lse_kernel(
    const bf16_t* __restrict__ A, const bf16_t* __restrict__ B,
    float* __restrict__ S)
{
    __shared__ bf16_t As[BM * BK];   // row-major, row stride BK (no padding: global_load_lds)
    __shared__ bf16_t Bs[BN * BK];

    const int t     = threadIdx.x;
    const int lane  = t & 63;
    const int w     = t >> 6;        // wave id 0..3
    const int waveM = w >> 1;        // 2x2 wave grid, each wave 64x64
    const int waveN = w & 1;
    const int lr    = lane & 15;          // row-in-16-tile (A) / col (B)
    const int lk    = (lane >> 4) * 8;    // k-offset within 32

    const int rowA0 = blockIdx.y * BM;
    const int rowB0 = blockIdx.x * BN;
    const bf16_t* Ablk = A + (size_t)rowA0 * DIM;
    const bf16_t* Bblk = B + (size_t)rowB0 * DIM;

    f32x4 acc[4][4] = {};

    for (int k0 = 0; k0 < DIM; k0 += BK) {
        __syncthreads();   // previous tile's compute done before overwrite
#pragma unroll
        for (int is = 0; is < 4; ++is) {
            const int c   = is * 256 + t;      // 16B chunk index within tile
            const int row = c >> 3;
            const int col = (c & 7) * 8;
            const bf16_t* ga = Ablk + (size_t)row * DIM + k0 + col;
            const bf16_t* gb = Bblk + (size_t)row * DIM + k0 + col;
            // LDS dest: wave-uniform base; HW adds lane*16
            bf16_t* la = &As[(size_t)(is * 256 + w * 64) * 8];
            bf16_t* lb = &Bs[(size_t)(is * 256 + w * 64) * 8];
            __builtin_amdgcn_global_load_lds(
                (const __attribute__((address_space(1))) void*)ga,
                (__attribute__((address_space(3))) void*)la, 16, 0, 0);
            __builtin_amdgcn_global_load_lds(
                (const __attribute__((address_space(1))) void*)gb,
                (__attribute__((address_space(3))) void*)lb, 16, 0, 0);
        }
        __syncthreads();   // staging complete (compiler drains vmcnt)

#pragma unroll
        for (int kk = 0; kk < BK; kk += 32) {
            bf16x8 af[4], bfr[4];
#pragma unroll
            for (int mi = 0; mi < 4; ++mi)
                af[mi] = *(const bf16x8*)&As[(waveM * 64 + mi * 16 + lr) * BK + kk + lk];
#pragma unroll
            for (int ni = 0; ni < 4; ++ni)
                bfr[ni] = *(const bf16x8*)&Bs[(waveN * 64 + ni * 16 + lr) * BK + kk + lk];
#pragma unroll
            for (int mi = 0; mi < 4; ++mi)
#pragma unroll
                for (int ni = 0; ni < 4; ++ni)
                    acc[mi][ni] = __builtin_amdgcn_mfma_f32_16x16x32_bf16(
                        af[mi], bfr[ni], acc[mi][ni], 0, 0, 0);
        }
    }

    // Epilogue: exp(s-1), sum across this block's 128 columns, atomic into S.
    // C/D layout (m89-verified): col = lane&15, row = (lane>>4)*4 + reg
    const float L2E = 1.44269504088896f;
    const int rowbase = rowA0 + waveM * 64;
#pragma unroll
    for (int mi = 0; mi < 4; ++mi) {
        float p0 = 0.f, p1 = 0.f, p2 = 0.f, p3 = 0.f;
#pragma unroll
        for (int ni = 0; ni < 4; ++ni) {
            p0 += exp2f(acc[mi][ni].x * L2E - L2E);
            p1 += exp2f(acc[mi][ni].y * L2E - L2E);
            p2 += exp2f(acc[mi][ni].z * L2E - L2E);
            p3 += exp2f(acc[mi][ni].w * L2E - L2E);
        }
#pragma unroll
        for (int d = 1; d < 16; d <<= 1) {   // reduce across the 16 column-lanes
            p0 += __shfl_xor(p0, d, 64);
            p1 += __shfl_xor(p1, d, 64);
            p2 += __shfl_xor(p2, d, 64);
            p3 += __shfl_xor(p3, d, 64);
        }
        if ((lane & 15) == 0) {
            float* dst = &S[rowbase + mi * 16 + (lane >> 4) * 4];
            atomicAdd(dst + 0, p0);
            atomicAdd(dst + 1, p1);
            atomicAdd(dst + 2, p2);
            atomicAdd(dst + 3, p3);
        }
    }
}

// ---------------------------------------------------------------------------
// Kernel 3: out = mean(log(S_i)) - mean(diag)
// ---------------------------------------------------------------------------
__global__ __launch_bounds__(256) void fin_kernel(
    const float* __restrict__ S, const float* __restrict__ diag_sum,
    float* __restrict__ out)
{
    const int t = threadIdx.x;
    float s = 0.f;
    for (int i = t; i < N_ROWS; i += 256) s += logf(S[i]);
#pragma unroll
    for (int d = 1; d < 64; d <<= 1) s += __shfl_xor(s, d, 64);
    __shared__ float red[4];
    if ((t & 63) == 0) red[t >> 6] = s;
    __syncthreads();
    if (t == 0)
        out[0] = (red[0] + red[1] + red[2] + red[3] - diag_sum[0]) * (1.0f / N_ROWS);
}

// ---------------------------------------------------------------------------
extern "C" void kernel_launch(void* const* d_in, const int* in_sizes, int n_in,
                              void* d_out, int out_size, void* d_ws, size_t ws_size,
                              hipStream_t stream)
{
    const float* img = (const float*)d_in[0];
    const float* txt = (const float*)d_in[1];
    float* out = (float*)d_out;

    char* ws = (char*)d_ws;
    bf16_t* img_n   = (bf16_t*)ws;                                   // 16 MiB
    bf16_t* txt_n   = (bf16_t*)(ws + (size_t)N_ROWS * DIM * 2);      // 16 MiB
    float*  S       = (float*)(ws + (size_t)N_ROWS * DIM * 4);       // 32 KiB
    float*  diag_sum = S + N_ROWS;

    hipMemsetAsync(S, 0, (N_ROWS + 1) * sizeof(float), stream);
    nrm_kernel<<<N_ROWS, 256, 0, stream>>>(img, txt, img_n, txt_n, diag_sum);
    dim3 grid(N_ROWS / BN, N_ROWS / BM);
    sim_lse_kernel<<<grid, 256, 0, stream>>>(img_n, txt_n, S);
    fin_kernel<<<1, 256, 0, stream>>>(S, diag_sum, out);
}

// Round 2
// 324.444 us; speedup vs baseline: 1.3963x; 1.3963x over previous
//
#include <hip/hip_runtime.h>
#include <hip/hip_bf16.h>
#include <stdint.h>

#define N_ROWS 8192
#define DIM    1024
#define BM 128
#define BN 128
#define BK 64

typedef __bf16 bf16_t;
typedef __bf16 bf16x4 __attribute__((ext_vector_type(4)));
typedef __bf16 bf16x8 __attribute__((ext_vector_type(8)));
typedef float  f32x4  __attribute__((ext_vector_type(4)));

// ---------------------------------------------------------------------------
// Kernel 1: fused L2-normalize (fp32 -> bf16) + exact fp32 per-row diagonal.
// One block per row; 256 threads x float4 = 1024 elements.
// No global atomics (R1: single-address atomicAdd hotspot cost ~100+ us).
// ---------------------------------------------------------------------------
__global__ __launch_bounds__(256) void nrm_kernel(
    const float* __restrict__ img, const float* __restrict__ txt,
    bf16_t* __restrict__ img_n, bf16_t* __restrict__ txt_n,
    float* __restrict__ diag)
{
    const int row  = blockIdx.x;
    const int t    = threadIdx.x;
    const int lane = t & 63;
    const int w    = t >> 6;

    const float4 a = ((const float4*)(img + (size_t)row * DIM))[t];
    const float4 b = ((const float4*)(txt + (size_t)row * DIM))[t];

    float sa = a.x * a.x + a.y * a.y + a.z * a.z + a.w * a.w;
    float sb = b.x * b.x + b.y * b.y + b.z * b.z + b.w * b.w;
#pragma unroll
    for (int d = 1; d < 64; d <<= 1) {
        sa += __shfl_xor(sa, d, 64);
        sb += __shfl_xor(sb, d, 64);
    }
    __shared__ float red[3][4];
    if (lane == 0) { red[0][w] = sa; red[1][w] = sb; }
    __syncthreads();
    sa = red[0][0] + red[0][1] + red[0][2] + red[0][3];
    sb = red[1][0] + red[1][1] + red[1][2] + red[1][3];

    const float ia = 1.0f / fmaxf(sqrtf(sa), 1e-12f);
    const float ib = 1.0f / fmaxf(sqrtf(sb), 1e-12f);

    bf16x4 av, bv;
    av.x = (bf16_t)(a.x * ia); av.y = (bf16_t)(a.y * ia);
    av.z = (bf16_t)(a.z * ia); av.w = (bf16_t)(a.w * ia);
    bv.x = (bf16_t)(b.x * ib); bv.y = (bf16_t)(b.y * ib);
    bv.z = (bf16_t)(b.z * ib); bv.w = (bf16_t)(b.w * ib);
    ((bf16x4*)(img_n + (size_t)row * DIM))[t] = av;
    ((bf16x4*)(txt_n + (size_t)row * DIM))[t] = bv;

    // exact fp32 diagonal (positives), one plain store per row
    float dp = (a.x * b.x + a.y * b.y + a.z * b.z + a.w * b.w) * ia * ib;
#pragma unroll
    for (int d = 1; d < 64; d <<= 1) dp += __shfl_xor(dp, d, 64);
    if (lane == 0) red[2][w] = dp;
    __syncthreads();
    if (t == 0) diag[row] = red[2][0] + red[2][1] + red[2][2] + red[2][3];
}

// ---------------------------------------------------------------------------
// Kernel 2: 128x128-tile bf16 MFMA GEMM (C = A . B^T), fused epilogue:
// rowsum of exp(sim - 1) -> atomicAdd into S[row].
// R1 change: XOR-swizzled LDS layout. Row r's 16B chunk c is stored at LDS
// chunk (c ^ (r&7)) by permuting the GLOBAL source address per lane (the
// global_load_lds LDS destination stays lane-ordered, as required). This
// spreads each ds_read_b128's 64 lanes across all 32 banks (was: 16 banks,
// 16-way quad aliasing -> SQ_LDS_BANK_CONFLICT 5e7).
// ---------------------------------------------------------------------------
__global__ __launch_bounds__(256) void sim_lse_kernel(
    const bf16_t* __restrict__ A, const bf16_t* __restrict__ B,
    float* __restrict__ S)
{
    __shared__ bf16_t As[BM * BK];
    __shared__ bf16_t Bs[BN * BK];

    const int t     = threadIdx.x;
    const int lane  = t & 63;
    const int w     = t >> 6;        // wave id 0..3
    const int waveM = w >> 1;        // 2x2 wave grid, each wave 64x64
    const int waveN = w & 1;
    const int lr    = lane & 15;          // row-in-16-tile
    const int lk    = (lane >> 4) * 8;    // k-element offset within 32
    const int swz   = lr & 7;             // read-side XOR swizzle key

    const int rowA0 = blockIdx.y * BM;
    const int rowB0 = blockIdx.x * BN;
    const bf16_t* Ablk = A + (size_t)rowA0 * DIM;
    const bf16_t* Bblk = B + (size_t)rowB0 * DIM;

    f32x4 acc[4][4] = {};

    for (int k0 = 0; k0 < DIM; k0 += BK) {
        __syncthreads();   // previous tile's compute done before overwrite
#pragma unroll
        for (int is = 0; is < 4; ++is) {
            const int c    = is * 256 + t;       // LDS 16B-chunk position
            const int row  = c >> 3;
            const int scol = c & 7;
            const int col  = scol ^ (row & 7);   // swizzled source chunk
            const bf16_t* ga = Ablk + (size_t)row * DIM + k0 + col * 8;
            const bf16_t* gb = Bblk + (size_t)row * DIM + k0 + col * 8;
            bf16_t* la = &As[(size_t)(is * 256 + w * 64) * 8];
            bf16_t* lb = &Bs[(size_t)(is * 256 + w * 64) * 8];
            __builtin_amdgcn_global_load_lds(
                (const __attribute__((address_space(1))) void*)ga,
                (__attribute__((address_space(3))) void*)la, 16, 0, 0);
            __builtin_amdgcn_global_load_lds(
                (const __attribute__((address_space(1))) void*)gb,
                (__attribute__((address_space(3))) void*)lb, 16, 0, 0);
        }
        __syncthreads();   // staging complete

#pragma unroll
        for (int kk = 0; kk < BK; kk += 32) {
            const int kc = (kk + lk) >> 3;           // chunk index 0..7
            const int sc = (kc ^ swz) << 3;          // swizzled, in elements
            bf16x8 af[4], bfr[4];
#pragma unroll
            for (int mi = 0; mi < 4; ++mi)
                af[mi] = *(const bf16x8*)&As[(waveM * 64 + mi * 16 + lr) * BK + sc];
#pragma unroll
            for (int ni = 0; ni < 4; ++ni)
                bfr[ni] = *(const bf16x8*)&Bs[(waveN * 64 + ni * 16 + lr) * BK + sc];
#pragma unroll
            for (int mi = 0; mi < 4; ++mi)
#pragma unroll
                for (int ni = 0; ni < 4; ++ni)
                    acc[mi][ni] = __builtin_amdgcn_mfma_f32_16x16x32_bf16(
                        af[mi], bfr[ni], acc[mi][ni], 0, 0, 0);
        }
    }

    // Epilogue: exp(s-1), sum across this block's 128 columns, atomic into S.
    // C/D layout (m89-verified): col = lane&15, row = (lane>>4)*4 + reg
    const float L2E = 1.44269504088896f;
    const int rowbase = rowA0 + waveM * 64;
#pragma unroll
    for (int mi = 0; mi < 4; ++mi) {
        float p0 = 0.f, p1 = 0.f, p2 = 0.f, p3 = 0.f;
#pragma unroll
        for (int ni = 0; ni < 4; ++ni) {
            p0 += exp2f(acc[mi][ni].x * L2E - L2E);
            p1 += exp2f(acc[mi][ni].y * L2E - L2E);
            p2 += exp2f(acc[mi][ni].z * L2E - L2E);
            p3 += exp2f(acc[mi][ni].w * L2E - L2E);
        }
#pragma unroll
        for (int d = 1; d < 16; d <<= 1) {
            p0 += __shfl_xor(p0, d, 64);
            p1 += __shfl_xor(p1, d, 64);
            p2 += __shfl_xor(p2, d, 64);
            p3 += __shfl_xor(p3, d, 64);
        }
        if ((lane & 15) == 0) {
            float* dst = &S[rowbase + mi * 16 + (lane >> 4) * 4];
            atomicAdd(dst + 0, p0);
            atomicAdd(dst + 1, p1);
            atomicAdd(dst + 2, p2);
            atomicAdd(dst + 3, p3);
        }
    }
}

// ---------------------------------------------------------------------------
// Kernel 3: out = mean(log(S_i) - diag_i)
// ---------------------------------------------------------------------------
__global__ __launch_bounds__(1024) void fin_kernel(
    const float* __restrict__ S, const float* __restrict__ diag,
    float* __restrict__ out)
{
    const int t = threadIdx.x;
    float s = 0.f;
    for (int i = t; i < N_ROWS; i += 1024) s += logf(S[i]) - diag[i];
#pragma unroll
    for (int d = 1; d < 64; d <<= 1) s += __shfl_xor(s, d, 64);
    __shared__ float red[16];
    if ((t & 63) == 0) red[t >> 6] = s;
    __syncthreads();
    if (t == 0) {
        float tot = 0.f;
#pragma unroll
        for (int i = 0; i < 16; ++i) tot += red[i];
        out[0] = tot * (1.0f / N_ROWS);
    }
}

// ---------------------------------------------------------------------------
extern "C" void kernel_launch(void* const* d_in, const int* in_sizes, int n_in,
                              void* d_out, int out_size, void* d_ws, size_t ws_size,
                              hipStream_t stream)
{
    const float* img = (const float*)d_in[0];
    const float* txt = (const float*)d_in[1];
    float* out = (float*)d_out;

    char* ws = (char*)d_ws;
    bf16_t* img_n = (bf16_t*)ws;                                   // 16 MiB
    bf16_t* txt_n = (bf16_t*)(ws + (size_t)N_ROWS * DIM * 2);      // 16 MiB
    float*  S     = (float*)(ws + (size_t)N_ROWS * DIM * 4);       // 32 KiB
    float*  diag  = S + N_ROWS;                                    // 32 KiB

    hipMemsetAsync(S, 0, N_ROWS * sizeof(float), stream);
    nrm_kernel<<<N_ROWS, 256, 0, stream>>>(img, txt, img_n, txt_n, diag);
    dim3 grid(N_ROWS / BN, N_ROWS / BM);
    sim_lse_kernel<<<grid, 256, 0, stream>>>(img_n, txt_n, S);
    fin_kernel<<<1, 1024, 0, stream>>>(S, diag, out);
}

// Round 3
// 244.683 us; speedup vs baseline: 1.8515x; 1.3260x over previous
//
#include <hip/hip_runtime.h>
#include <hip/hip_bf16.h>
#include <stdint.h>

#define N_ROWS 8192
#define DIM    1024
#define BM 128
#define BN 128
#define BKF 128   // fp8 elements (=bytes) of K per staging iter; one MFMA K

typedef float   f32x4  __attribute__((ext_vector_type(4)));
typedef int     i32x4  __attribute__((ext_vector_type(4)));
typedef int     i32x8  __attribute__((ext_vector_type(8)));

// ---------------------------------------------------------------------------
// Kernel 1: fused L2-normalize (fp32 -> fp8 e4m3) + exact fp32 per-row
// diagonal + S zero-init (folds the memset dispatch).
// One block per row; 256 threads x float4 = 1024 elements.
// ---------------------------------------------------------------------------
__global__ __launch_bounds__(256) void nrm_kernel(
    const float* __restrict__ img, const float* __restrict__ txt,
    uint8_t* __restrict__ img_f8, uint8_t* __restrict__ txt_f8,
    float* __restrict__ diag, float* __restrict__ S)
{
    const int row  = blockIdx.x;
    const int t    = threadIdx.x;
    const int lane = t & 63;
    const int w    = t >> 6;

    const float4 a = ((const float4*)(img + (size_t)row * DIM))[t];
    const float4 b = ((const float4*)(txt + (size_t)row * DIM))[t];

    float sa = a.x * a.x + a.y * a.y + a.z * a.z + a.w * a.w;
    float sb = b.x * b.x + b.y * b.y + b.z * b.z + b.w * b.w;
#pragma unroll
    for (int d = 1; d < 64; d <<= 1) {
        sa += __shfl_xor(sa, d, 64);
        sb += __shfl_xor(sb, d, 64);
    }
    __shared__ float red[3][4];
    if (lane == 0) { red[0][w] = sa; red[1][w] = sb; }
    __syncthreads();
    sa = red[0][0] + red[0][1] + red[0][2] + red[0][3];
    sb = red[1][0] + red[1][1] + red[1][2] + red[1][3];

    const float ia = 1.0f / fmaxf(sqrtf(sa), 1e-12f);
    const float ib = 1.0f / fmaxf(sqrtf(sb), 1e-12f);

    // pack 4 normalized elements -> 4 fp8 e4m3 bytes (RNE)
    int ra = 0, rb = 0;
    ra = __builtin_amdgcn_cvt_pk_fp8_f32(a.x * ia, a.y * ia, ra, false);
    ra = __builtin_amdgcn_cvt_pk_fp8_f32(a.z * ia, a.w * ia, ra, true);
    rb = __builtin_amdgcn_cvt_pk_fp8_f32(b.x * ib, b.y * ib, rb, false);
    rb = __builtin_amdgcn_cvt_pk_fp8_f32(b.z * ib, b.w * ib, rb, true);
    ((int*)(img_f8 + (size_t)row * DIM))[t] = ra;
    ((int*)(txt_f8 + (size_t)row * DIM))[t] = rb;

    // exact fp32 diagonal (positives), one plain store per row
    float dp = (a.x * b.x + a.y * b.y + a.z * b.z + a.w * b.w) * ia * ib;
#pragma unroll
    for (int d = 1; d < 64; d <<= 1) dp += __shfl_xor(dp, d, 64);
    if (lane == 0) red[2][w] = dp;
    __syncthreads();
    if (t == 0) {
        diag[row] = red[2][0] + red[2][1] + red[2][2] + red[2][3];
        S[row] = 0.0f;   // init for sim_lse's atomics (replaces memset)
    }
}

// ---------------------------------------------------------------------------
// Kernel 2: 128x128-tile MX-fp8 MFMA GEMM (C = A . B^T), K=128 per MFMA
// (mfma_scale_f32_16x16x128_f8f6f4, fmt fp8-e4m3, scale e8m0=127 -> 1.0).
// Fused epilogue: rowsum of exp(sim - 1) -> atomicAdd into S[row].
// LDS: row = 128 B = 8 x 16B chunks; chunk c of row r stored at c^(r&7)
// (XOR swizzle via permuted GLOBAL source addresses; global_load_lds dest
// stays lane-ordered). R2 verified this swizzle gives 0 bank conflicts.
// ---------------------------------------------------------------------------
__global__ __launch_bounds__(256) void sim_lse_kernel(
    const uint8_t* __restrict__ A, const uint8_t* __restrict__ B,
    float* __restrict__ S)
{
    __shared__ __align__(16) uint8_t As[BM * BKF];   // 16 KiB
    __shared__ __align__(16) uint8_t Bs[BN * BKF];   // 16 KiB

    const int t     = threadIdx.x;
    const int lane  = t & 63;
    const int w     = t >> 6;        // wave id 0..3
    const int waveM = w >> 1;        // 2x2 wave grid, each wave 64x64
    const int waveN = w & 1;
    const int lr    = lane & 15;     // row-in-16-tile (A) / col (B)
    const int q     = lane >> 4;     // k-quarter: k = q*32 + j (f8f6f4 frag)
    const int swz   = lr & 7;        // read-side XOR swizzle key

    const int rowA0 = blockIdx.y * BM;
    const int rowB0 = blockIdx.x * BN;
    const uint8_t* Ablk = A + (size_t)rowA0 * DIM;
    const uint8_t* Bblk = B + (size_t)rowB0 * DIM;

    f32x4 acc[4][4] = {};

    for (int k0 = 0; k0 < DIM; k0 += BKF) {
        __syncthreads();   // previous tile's compute done before overwrite
#pragma unroll
        for (int is = 0; is < 4; ++is) {
            const int c    = is * 256 + t;       // LDS 16B-chunk position
            const int row  = c >> 3;             // tile row (128B rows)
            const int scol = c & 7;
            const int col  = scol ^ (row & 7);   // swizzled source chunk
            const uint8_t* ga = Ablk + (size_t)row * DIM + k0 + col * 16;
            const uint8_t* gb = Bblk + (size_t)row * DIM + k0 + col * 16;
            uint8_t* la = &As[(size_t)(is * 256 + w * 64) * 16];
            uint8_t* lb = &Bs[(size_t)(is * 256 + w * 64) * 16];
            __builtin_amdgcn_global_load_lds(
                (const __attribute__((address_space(1))) void*)ga,
                (__attribute__((address_space(3))) void*)la, 16, 0, 0);
            __builtin_amdgcn_global_load_lds(
                (const __attribute__((address_space(1))) void*)gb,
                (__attribute__((address_space(3))) void*)lb, 16, 0, 0);
        }
        __syncthreads();   // staging complete

        // Fragments: lane holds k = q*32..q*32+31 of row (waveM*64+mi*16+lr)
        // = source chunks {2q, 2q+1}, each at LDS chunk (c ^ swz).
        i32x8 af[4], bfr[4];
#pragma unroll
        for (int mi = 0; mi < 4; ++mi) {
            const uint8_t* base = &As[(waveM * 64 + mi * 16 + lr) * BKF];
            i32x4 lo = *(const i32x4*)&base[((2 * q) ^ swz) * 16];
            i32x4 hi = *(const i32x4*)&base[((2 * q + 1) ^ swz) * 16];
            af[mi] = (i32x8){lo.x, lo.y, lo.z, lo.w, hi.x, hi.y, hi.z, hi.w};
        }
#pragma unroll
        for (int ni = 0; ni < 4; ++ni) {
            const uint8_t* base = &Bs[(waveN * 64 + ni * 16 + lr) * BKF];
            i32x4 lo = *(const i32x4*)&base[((2 * q) ^ swz) * 16];
            i32x4 hi = *(const i32x4*)&base[((2 * q + 1) ^ swz) * 16];
            bfr[ni] = (i32x8){lo.x, lo.y, lo.z, lo.w, hi.x, hi.y, hi.z, hi.w};
        }
#pragma unroll
        for (int mi = 0; mi < 4; ++mi)
#pragma unroll
            for (int ni = 0; ni < 4; ++ni)
                acc[mi][ni] = __builtin_amdgcn_mfma_scale_f32_16x16x128_f8f6f4(
                    af[mi], bfr[ni], acc[mi][ni],
                    0 /*fmtA=fp8*/, 0 /*fmtB=fp8*/,
                    0, 127 /*scaleA=1.0*/, 0, 127 /*scaleB=1.0*/);
    }

    // Epilogue: exp(s-1), sum across this block's 128 columns, atomic into S.
    // C/D layout (shape-determined, dtype-independent; m89/m121-128):
    // col = lane&15, row = (lane>>4)*4 + reg
    const float L2E = 1.44269504088896f;
    const int rowbase = rowA0 + waveM * 64;
#pragma unroll
    for (int mi = 0; mi < 4; ++mi) {
        float p0 = 0.f, p1 = 0.f, p2 = 0.f, p3 = 0.f;
#pragma unroll
        for (int ni = 0; ni < 4; ++ni) {
            p0 += exp2f(acc[mi][ni].x * L2E - L2E);
            p1 += exp2f(acc[mi][ni].y * L2E - L2E);
            p2 += exp2f(acc[mi][ni].z * L2E - L2E);
            p3 += exp2f(acc[mi][ni].w * L2E - L2E);
        }
#pragma unroll
        for (int d = 1; d < 16; d <<= 1) {
            p0 += __shfl_xor(p0, d, 64);
            p1 += __shfl_xor(p1, d, 64);
            p2 += __shfl_xor(p2, d, 64);
            p3 += __shfl_xor(p3, d, 64);
        }
        if ((lane & 15) == 0) {
            float* dst = &S[rowbase + mi * 16 + (lane >> 4) * 4];
            atomicAdd(dst + 0, p0);
            atomicAdd(dst + 1, p1);
            atomicAdd(dst + 2, p2);
            atomicAdd(dst + 3, p3);
        }
    }
}

// ---------------------------------------------------------------------------
// Kernel 3: out = mean(log(S_i) - diag_i)
// ---------------------------------------------------------------------------
__global__ __launch_bounds__(1024) void fin_kernel(
    const float* __restrict__ S, const float* __restrict__ diag,
    float* __restrict__ out)
{
    const int t = threadIdx.x;
    float s = 0.f;
    for (int i = t; i < N_ROWS; i += 1024) s += logf(S[i]) - diag[i];
#pragma unroll
    for (int d = 1; d < 64; d <<= 1) s += __shfl_xor(s, d, 64);
    __shared__ float red[16];
    if ((t & 63) == 0) red[t >> 6] = s;
    __syncthreads();
    if (t == 0) {
        float tot = 0.f;
#pragma unroll
        for (int i = 0; i < 16; ++i) tot += red[i];
        out[0] = tot * (1.0f / N_ROWS);
    }
}

// ---------------------------------------------------------------------------
extern "C" void kernel_launch(void* const* d_in, const int* in_sizes, int n_in,
                              void* d_out, int out_size, void* d_ws, size_t ws_size,
                              hipStream_t stream)
{
    const float* img = (const float*)d_in[0];
    const float* txt = (const float*)d_in[1];
    float* out = (float*)d_out;

    char* ws = (char*)d_ws;
    uint8_t* img_f8 = (uint8_t*)ws;                                  // 8 MiB
    uint8_t* txt_f8 = (uint8_t*)(ws + (size_t)N_ROWS * DIM);         // 8 MiB
    float*   S      = (float*)(ws + (size_t)N_ROWS * DIM * 2);       // 32 KiB
    float*   diag   = S + N_ROWS;                                    // 32 KiB

    nrm_kernel<<<N_ROWS, 256, 0, stream>>>(img, txt, img_f8, txt_f8, diag, S);
    dim3 grid(N_ROWS / BN, N_ROWS / BM);
    sim_lse_kernel<<<grid, 256, 0, stream>>>(img_f8, txt_f8, S);
    fin_kernel<<<1, 1024, 0, stream>>>(S, diag, out);
}